// Round 5
// baseline (174.707 us; speedup 1.0000x reference)
//
#include <hip/hip_runtime.h>

// AdditiveAttention: B=4, Q=256, K=1024, DQ=DK=DV=512, H=128
#define B_ 4
#define Q_ 256
#define K_ 1024
#define D_ 512
#define H_ 128
#define DV_ 512
#define LOG2E 1.4426950408889634f

// tanh via exp2: tanh(x) = 1 - 2/(1+e^{2x}).  SUM_h w_h cancels in softmax:
// p = exp2( SUM_h (-2*log2e*w_h) * rcp(1 + exp2(2*log2e*(qh+kh))) ).
//
// Round-5: last-arrival fusion.  The 4-kernel chain spent ~7-10 us on two
// trailing reduction kernels (proj_reduce, finalize) that each require a full
// pipeline drain.  Both are now folded into their producer kernels: the last
// block to finish a tile/group (arrival counter, one atomicAdd per block)
// performs the reduction, overlapped with other tiles still computing.
// Protocol per producer block: stores -> __syncthreads() (per-thread vmcnt
// drain) -> t0 __threadfence() (agent release, L2 wb) -> t0 atomicAdd ->
// flag via LDS -> last block __threadfence() (acquire) -> reduce.
// Counters (288 ints) zeroed by a 1.2 KB hipMemsetAsync each call.

// ---------------------------------------------------------------------------
// proj_part: tile = 32 rows x 128 h x 128 d (2 LDS chunks of 64 d).
// Grid 640 = [ds:4 == bid&3][tile:160 = 32 q + 128 k].  4 waves = h-quadrants,
// lane micro 4r x 4h.  40 KB LDS, XOR-swizzled transposed staging.
// Tail: last ds-block of each tile sums the 4 psum slices, scales by
// 2*log2e, writes qh_s / kh4 (proj_reduce fused away).
// ---------------------------------------------------------------------------
__global__ __launch_bounds__(256) void proj_part(
    const float* __restrict__ qin, const float* __restrict__ kin,
    const float* __restrict__ wq,  const float* __restrict__ wk,
    const int* __restrict__ valid_lens, float* __restrict__ psum,
    float* __restrict__ qh_s, float* __restrict__ khf,
    int* __restrict__ cnt_tile)
{
    __shared__ float Xs[64 * 32];    //  8 KB, [d][row],  col ^= ((d>>2)&7)<<2
    __shared__ float Ws[64 * 128];   // 32 KB, [d][h],    col ^= ((d>>2)&7)<<2
    __shared__ int lastf;

    const int t = threadIdx.x, bid = blockIdx.x;
    const int ds = bid & 3, tile = bid >> 2;     // tile 0..159
    const float* X; const float* W;
    int R0;
    if (tile < 32) { X = qin + (size_t)tile * 32 * D_; W = wq; R0 = tile * 32; }
    else {
        int kt = tile - 32, kb = kt >> 5, kr0 = (kt & 31) * 32;
        if (kr0 >= valid_lens[kb]) return;
        X = kin + ((size_t)kb * K_ + kr0) * D_;
        W = wk;
        R0 = 1024 + kt * 32;
    }

    const int xrow  = (t + 0) >> 4, xdq = (t & 15) * 4;
    const int xrow1 = (t + 256) >> 4;
    float4 xr0, xr1, wr8[8];

    #define LOADX(c) do { \
        xr0 = *(const float4*)&X[(size_t)xrow  * D_ + (c)*64 + xdq]; \
        xr1 = *(const float4*)&X[(size_t)xrow1 * D_ + (c)*64 + xdq]; } while (0)
    #define LOADW(c) do { \
        _Pragma("unroll") \
        for (int i = 0; i < 8; ++i) { \
            int idx = t + i * 256; \
            wr8[i] = *(const float4*)&W[(size_t)(idx >> 4) * D_ + (c)*64 + (idx & 15) * 4]; } } while (0)
    #define WRITE_LDS() do { \
        { float v[4]; *(float4*)v = xr0; \
          _Pragma("unroll") \
          for (int j = 0; j < 4; ++j) { int d = xdq + j; \
              Xs[d * 32 + (xrow ^ (((d >> 2) & 7) << 2))] = v[j]; } } \
        { float v[4]; *(float4*)v = xr1; \
          _Pragma("unroll") \
          for (int j = 0; j < 4; ++j) { int d = xdq + j; \
              Xs[d * 32 + (xrow1 ^ (((d >> 2) & 7) << 2))] = v[j]; } } \
        _Pragma("unroll") \
        for (int i = 0; i < 8; ++i) { \
            int idx = t + i * 256; int h = idx >> 4, dq = (idx & 15) * 4; \
            float v[4]; *(float4*)v = wr8[i]; \
            _Pragma("unroll") \
            for (int j = 0; j < 4; ++j) { int d = dq + j; \
                Ws[d * 128 + (h ^ (((d >> 2) & 7) << 2))] = v[j]; } } } while (0)

    const int wid = t >> 6, lane = t & 63;
    const int r0 = (lane & 7) * 4;                    // 4 rows
    const int h0 = wid * 32 + (lane >> 3) * 4;        // 4 h
    float c[4][4] = {};

    const int c0 = ds * 2;                            // 2 chunks: c0, c0+1
    LOADX(c0); LOADW(c0);
    WRITE_LDS();

    for (int cc = 0; cc < 2; ++cc) {
        __syncthreads();                  // LDS chunk ready
        if (cc < 1) { LOADX(c0 + 1); LOADW(c0 + 1); }
#pragma unroll 8
        for (int kk = 0; kk < 64; ++kk) {
            const int xc = ((kk >> 2) & 7) << 2;
            float xr[4], wr[4];
            *(float4*)&xr[0] = *(const float4*)&Xs[kk * 32  + (r0 ^ xc)];
            *(float4*)&wr[0] = *(const float4*)&Ws[kk * 128 + (h0 ^ xc)];
#pragma unroll
            for (int i = 0; i < 4; ++i)
#pragma unroll
                for (int j = 0; j < 4; ++j) c[i][j] = fmaf(xr[i], wr[j], c[i][j]);
        }
        __syncthreads();                  // all reads done
        if (cc < 1) WRITE_LDS();
    }

    float* outp = psum + ((size_t)ds * 5120 + R0) * 128;
#pragma unroll
    for (int i = 0; i < 4; ++i)
        *(float4*)&outp[(size_t)(r0 + i) * 128 + h0] = *(const float4*)&c[i][0];

    // ---- last-arrival fused reduce (replaces proj_reduce kernel) ----
    __syncthreads();                      // per-thread vmcnt drain: stores in L2
    if (t == 0) {
        __threadfence();                  // agent release: L2 writeback
        int old = atomicAdd(&cnt_tile[tile], 1);
        lastf = (old == 3);
    }
    __syncthreads();
    if (!lastf) return;
    __threadfence();                      // acquire side

    const float SC = 2.0f * LOG2E;
#pragma unroll
    for (int u = 0; u < 4; ++u) {
        int unit = t + u * 256;           // 1024 units = 32 rows x 32 c4
        int r = unit >> 5, c4 = unit & 31;
        float4 s = make_float4(0.f, 0.f, 0.f, 0.f);
#pragma unroll
        for (int d2 = 0; d2 < 4; ++d2) {
            float4 v = *(const float4*)&psum[((size_t)d2 * 5120 + R0 + r) * 128 + c4 * 4];
            s.x += v.x; s.y += v.y; s.z += v.z; s.w += v.w;
        }
        s.x *= SC; s.y *= SC; s.z *= SC; s.w *= SC;
        if (tile < 32) {
            *(float4*)&qh_s[(size_t)(tile * 32 + r) * 128 + c4 * 4] = s;
        } else {
            int kt = tile - 32, kb = kt >> 5, kr0 = (kt & 31) * 32;
            size_t idx = ((size_t)kb * 32 + c4) * K_ + (kr0 + r);
            *(float4*)&khf[idx * 4] = s;
        }
    }
    #undef LOADX
    #undef LOADW
    #undef WRITE_LDS
}

// ---------------------------------------------------------------------------
// attn_part: 2048 blocks x 256 thr (4 waves), item = (b, 8-q tile, 64-k
// chunk); ~1024 active -> ~16+ waves/CU.  31.3 KB LDS -> 5 blocks/CU.
// Phase B: 4-way h-split (hh = wave, 8 hq each), kh prefetch depth 1,
// exp2-tanh (3 VALU + 2 trans / element), 256 elements/thread.
// Combine: all 4 waves, 2 q-rows each.  Phase D: 2-way k-split, v prefetch.
// Tail: last active block of the (b,qt) group sums o_part/s_part across its
// nch chunks and writes out (finalize fused away).
// ---------------------------------------------------------------------------
__global__ __launch_bounds__(256) void attn_part(
    const float* __restrict__ qh_s, const float4* __restrict__ kh4,
    const float* __restrict__ wvg,  const int* __restrict__ valid_lens,
    const float* __restrict__ vin,
    float* __restrict__ s_part, float4* __restrict__ o_part,
    int* __restrict__ cnt_grp, float4* __restrict__ out)
{
    __shared__ float  qv[1024];
    __shared__ float  wvs[128];
    __shared__ float  ptmp[4][8][64];
    __shared__ float  p[8][64];
    __shared__ float  sred[8];
    __shared__ float4 otmp[8][128];
    __shared__ int    lastf;

    const int t   = threadIdx.x;
    const int bid = blockIdx.x;
    const int qt  = bid & 31, kc = (bid >> 5) & 15, b = bid >> 9;
    const int q0  = qt * 8;
    const int vl  = valid_lens[b];
    const int kbase = kc * 64;
    if (kbase >= vl) return;
    const int klen = min(64, vl - kbase);
    const int nch  = (vl + 63) >> 6;

#pragma unroll
    for (int i = 0; i < 4; ++i)
        qv[t + i * 256] = qh_s[(size_t)(b*Q_ + q0) * H_ + t + i * 256];
    if (t < 128) wvs[t] = wvg[t] * (-2.0f * LOG2E);
    __syncthreads();

    const int k  = t & 63;              // k within chunk
    const int hh = t >> 6;              // h-quarter (== wave id)
    const bool active = k < klen;

    // ---- Phase B: scores (4-way h-split, kh prefetch depth 1) ----
    float acc[8] = {};
    if (active) {
        const float4* khp = kh4 + (size_t)b * 32 * K_ + (kbase + k)
                          + (size_t)(hh * 8) * K_;
        const int hq0 = hh * 8;
        float4 kxn = khp[0];
#pragma unroll
        for (int i = 0; i < 8; ++i) {
            float4 kx = kxn;
            int ni = (i < 7) ? i + 1 : 7;
            kxn = khp[(size_t)ni * K_];
            const int hq = hq0 + i;
            float w4[4], kxa[4];
            *(float4*)&w4[0]  = *(const float4*)&wvs[hq*4];
            *(float4*)&kxa[0] = kx;
#pragma unroll
            for (int qi = 0; qi < 8; ++qi) {
                float q4[4];
                *(float4*)&q4[0] = *(const float4*)&qv[qi*128 + hq*4];
#pragma unroll
                for (int j = 0; j < 4; ++j) {
                    float tt = __builtin_amdgcn_exp2f(q4[j] + kxa[j]);
                    float rr = __builtin_amdgcn_rcpf(tt + 1.0f);
                    acc[qi] = fmaf(w4[j], rr, acc[qi]);
                }
            }
        }
    }
#pragma unroll
    for (int qi = 0; qi < 8; ++qi) ptmp[hh][qi][k] = acc[qi];
    __syncthreads();

    // ---- combine: each wave finishes 2 q-rows ----
    {
        const int qia = hh * 2;
#pragma unroll
        for (int q2 = 0; q2 < 2; ++q2) {
            const int qi = qia + q2;
            float a = ptmp[0][qi][k] + ptmp[1][qi][k]
                    + ptmp[2][qi][k] + ptmp[3][qi][k];
            float e = active ? __builtin_amdgcn_exp2f(a) : 0.f;
            p[qi][k] = e;
            float s = e;
#pragma unroll
            for (int off = 32; off > 0; off >>= 1) s += __shfl_xor(s, off);
            if (k == 0) sred[qi] = s;
        }
    }
    __syncthreads();                    // p + sred ready

    if (t < 8)
        s_part[(size_t)(b*Q_ + q0 + t) * 16 + kc] = sred[t];

    // ---- Phase D: partial PV (2-way k-split, v prefetch one 4-group) ----
    const int col  = t & 127;           // float4 column of DV/4
    const int half = t >> 7;
    const int kb2  = half * 32;
    const int ke2  = min(klen, kb2 + 32);
    const float4* vb = (const float4*)vin + (size_t)b * K_ * 128
                     + (size_t)kbase * 128;

    float4 o[8];
#pragma unroll
    for (int qi = 0; qi < 8; ++qi) o[qi] = make_float4(0.f, 0.f, 0.f, 0.f);

    int kk = kb2;
    const int nfull = (ke2 > kb2) ? ((ke2 - kb2) >> 2) : 0;
    if (nfull > 0) {
        float4 n0v = vb[(size_t)(kk+0)*128 + col];
        float4 n1v = vb[(size_t)(kk+1)*128 + col];
        float4 n2v = vb[(size_t)(kk+2)*128 + col];
        float4 n3v = vb[(size_t)(kk+3)*128 + col];
        for (int g = 0; g < nfull; ++g) {
            float4 v0 = n0v, v1 = n1v, v2 = n2v, v3 = n3v;
            int kn = kk + 4;
            if (g + 1 < nfull) {
                n0v = vb[(size_t)(kn+0)*128 + col];
                n1v = vb[(size_t)(kn+1)*128 + col];
                n2v = vb[(size_t)(kn+2)*128 + col];
                n3v = vb[(size_t)(kn+3)*128 + col];
            }
#pragma unroll
            for (int qi = 0; qi < 8; ++qi) {
                float4 pq = *(const float4*)&p[qi][kk];
                o[qi].x += pq.x*v0.x + pq.y*v1.x + pq.z*v2.x + pq.w*v3.x;
                o[qi].y += pq.x*v0.y + pq.y*v1.y + pq.z*v2.y + pq.w*v3.y;
                o[qi].z += pq.x*v0.z + pq.y*v1.z + pq.z*v2.z + pq.w*v3.z;
                o[qi].w += pq.x*v0.w + pq.y*v1.w + pq.z*v2.w + pq.w*v3.w;
            }
            kk = kn;
        }
    }
    for (; kk < ke2; ++kk) {
        float4 v0 = vb[(size_t)kk*128 + col];
#pragma unroll
        for (int qi = 0; qi < 8; ++qi) {
            float pk = p[qi][kk];
            o[qi].x += pk*v0.x; o[qi].y += pk*v0.y;
            o[qi].z += pk*v0.z; o[qi].w += pk*v0.w;
        }
    }

    if (half == 1) {
#pragma unroll
        for (int qi = 0; qi < 8; ++qi) otmp[qi][col] = o[qi];
    }
    __syncthreads();
    if (half == 0) {
#pragma unroll
        for (int qi = 0; qi < 8; ++qi) {
            float4 r = otmp[qi][col];
            o[qi].x += r.x; o[qi].y += r.y; o[qi].z += r.z; o[qi].w += r.w;
            o_part[((size_t)kc * 1024 + (b*Q_ + q0 + qi)) * 128 + col] = o[qi];
        }
    }

    // ---- last-arrival fused finalize (replaces finalize kernel) ----
    __syncthreads();                      // per-thread vmcnt drain
    if (t == 0) {
        __threadfence();                  // agent release
        int old = atomicAdd(&cnt_grp[b * 32 + qt], 1);
        lastf = (old == nch - 1);
    }
    __syncthreads();
    if (!lastf) return;
    __threadfence();                      // acquire side

#pragma unroll
    for (int u = 0; u < 4; ++u) {
        int unit = t + u * 256;           // 1024 units = 8 rows x 128 cols
        int r = unit >> 7, c = unit & 127;
        int row = b * Q_ + q0 + r;
        float ssum = 0.f;
        float4 os = make_float4(0.f, 0.f, 0.f, 0.f);
        for (int ch = 0; ch < nch; ++ch) {
            ssum += s_part[(size_t)row * 16 + ch];
            float4 rr = o_part[((size_t)ch * 1024 + row) * 128 + c];
            os.x += rr.x; os.y += rr.y; os.z += rr.z; os.w += rr.w;
        }
        float rs = __builtin_amdgcn_rcpf(ssum);
        out[(size_t)row * 128 + c] = make_float4(os.x*rs, os.y*rs, os.z*rs, os.w*rs);
    }
}

extern "C" void kernel_launch(void* const* d_in, const int* in_sizes, int n_in,
                              void* d_out, int out_size, void* d_ws, size_t ws_size,
                              hipStream_t stream)
{
    const float* q  = (const float*)d_in[0];
    const float* k  = (const float*)d_in[1];
    const float* v  = (const float*)d_in[2];
    const int*   vl = (const int*)d_in[3];
    const float* wq = (const float*)d_in[4];
    const float* wk = (const float*)d_in[5];
    const float* wv = (const float*)d_in[6];
    float* out = (float*)d_out;

    float* qh_s  = (float*)d_ws;                      //  131072 f
    float* kh4   = qh_s  + (size_t)B_*Q_*H_;          //  524288 f
    float* s_prt = kh4   + (size_t)B_*H_*K_;          //   16384 f
    float* o_prt = s_prt + (size_t)B_*Q_*16;          // 8388608 f (32 MB)
    float* psum  = o_prt + (size_t)16*B_*Q_*DV_;      // 2621440 f (10.5 MB)
    int*   cnt   = (int*)(psum + (size_t)4*5120*128); // 160 + 128 ints

    // zero arrival counters (1.2 KB, graph-safe)
    hipMemsetAsync(cnt, 0, 288 * sizeof(int), stream);

    proj_part<<<dim3(640),  dim3(256), 0, stream>>>(
        q, k, wq, wk, vl, psum, qh_s, kh4, cnt);
    attn_part<<<dim3(2048), dim3(256), 0, stream>>>(
        qh_s, (const float4*)kh4, wv, vl, v, s_prt, (float4*)o_prt,
        cnt + 160, (float4*)out);
}

// Round 6
// 115.093 us; speedup vs baseline: 1.5180x; 1.5180x over previous
//
#include <hip/hip_runtime.h>

// AdditiveAttention: B=4, Q=256, K=1024, DQ=DK=DV=512, H=128
#define B_ 4
#define Q_ 256
#define K_ 1024
#define D_ 512
#define H_ 128
#define DV_ 512
#define LOG2E 1.4426950408889634f

// tanh via exp2: tanh(x) = 1 - 2/(1+e^{2x}).  SUM_h w_h cancels in softmax:
// p = exp2( SUM_h (-2*log2e*w_h) * rcp(1 + exp2(2*log2e*(qh+kh))) ).
// 2*log2e folded at proj_reduce; -2*log2e into w_v at attn staging.
//
// Round-6: r4 baseline (115.3 us, reproduced) + attn occupancy fix.
// r3/r5 counters: attn family is LATENCY-bound (occ 9-17%, VALU 15-21%,
// HBM 5%).  r4 attn LDS 31.7 KB -> 5 blocks/CU; 16 KB of it was otmp,
// needed only by the k-split phase D.  Phase D now: each thread owns a
// float2 column (256 cols) x all 8 q-rows x full klen — same FMA and same
// bytes, but no otmp / no extra sync / no cross-half reduce; LDS ~14.6 KB,
// accumulators 16 VGPR.  (r5 lesson: no device-scope fences in hot kernels.)

// ---------------------------------------------------------------------------
// proj_part: tile = 32 rows x 128 h x 128 d (2 LDS chunks of 64 d).
// Grid 640 = [ds:4 == bid&3][tile:160 = 32 q + 128 k].  4 waves = h-quadrants,
// lane micro 4r x 4h.  40 KB LDS, XOR-swizzled transposed staging
// (write-conflict-free), next-chunk global loads overlap compute (T14).
// Epilogue: float4 partials -> psum[ds] (no atomics, no cross-block reduce).
// ---------------------------------------------------------------------------
__global__ __launch_bounds__(256) void proj_part(
    const float* __restrict__ qin, const float* __restrict__ kin,
    const float* __restrict__ wq,  const float* __restrict__ wk,
    const int* __restrict__ valid_lens, float* __restrict__ psum)
{
    __shared__ float Xs[64 * 32];    //  8 KB, [d][row],  col ^= ((d>>2)&7)<<2
    __shared__ float Ws[64 * 128];   // 32 KB, [d][h],    col ^= ((d>>2)&7)<<2

    const int t = threadIdx.x, bid = blockIdx.x;
    const int ds = bid & 3, tile = bid >> 2;     // tile 0..159
    const float* X; const float* W;
    int R0;
    if (tile < 32) { X = qin + (size_t)tile * 32 * D_; W = wq; R0 = tile * 32; }
    else {
        int kt = tile - 32, kb = kt >> 5, kr0 = (kt & 31) * 32;
        if (kr0 >= valid_lens[kb]) return;
        X = kin + ((size_t)kb * K_ + kr0) * D_;
        W = wk;
        R0 = 1024 + kt * 32;
    }

    const int xrow  = (t + 0) >> 4, xdq = (t & 15) * 4;
    const int xrow1 = (t + 256) >> 4;
    float4 xr0, xr1, wr8[8];

    #define LOADX(c) do { \
        xr0 = *(const float4*)&X[(size_t)xrow  * D_ + (c)*64 + xdq]; \
        xr1 = *(const float4*)&X[(size_t)xrow1 * D_ + (c)*64 + xdq]; } while (0)
    #define LOADW(c) do { \
        _Pragma("unroll") \
        for (int i = 0; i < 8; ++i) { \
            int idx = t + i * 256; \
            wr8[i] = *(const float4*)&W[(size_t)(idx >> 4) * D_ + (c)*64 + (idx & 15) * 4]; } } while (0)
    #define WRITE_LDS() do { \
        { float v[4]; *(float4*)v = xr0; \
          _Pragma("unroll") \
          for (int j = 0; j < 4; ++j) { int d = xdq + j; \
              Xs[d * 32 + (xrow ^ (((d >> 2) & 7) << 2))] = v[j]; } } \
        { float v[4]; *(float4*)v = xr1; \
          _Pragma("unroll") \
          for (int j = 0; j < 4; ++j) { int d = xdq + j; \
              Xs[d * 32 + (xrow1 ^ (((d >> 2) & 7) << 2))] = v[j]; } } \
        _Pragma("unroll") \
        for (int i = 0; i < 8; ++i) { \
            int idx = t + i * 256; int h = idx >> 4, dq = (idx & 15) * 4; \
            float v[4]; *(float4*)v = wr8[i]; \
            _Pragma("unroll") \
            for (int j = 0; j < 4; ++j) { int d = dq + j; \
                Ws[d * 128 + (h ^ (((d >> 2) & 7) << 2))] = v[j]; } } } while (0)

    const int wid = t >> 6, lane = t & 63;
    const int r0 = (lane & 7) * 4;                    // 4 rows
    const int h0 = wid * 32 + (lane >> 3) * 4;        // 4 h
    float c[4][4] = {};

    const int c0 = ds * 2;                            // 2 chunks: c0, c0+1
    LOADX(c0); LOADW(c0);
    WRITE_LDS();

    for (int cc = 0; cc < 2; ++cc) {
        __syncthreads();                  // LDS chunk ready
        if (cc < 1) { LOADX(c0 + 1); LOADW(c0 + 1); }
#pragma unroll 8
        for (int kk = 0; kk < 64; ++kk) {
            const int xc = ((kk >> 2) & 7) << 2;
            float xr[4], wr[4];
            *(float4*)&xr[0] = *(const float4*)&Xs[kk * 32  + (r0 ^ xc)];
            *(float4*)&wr[0] = *(const float4*)&Ws[kk * 128 + (h0 ^ xc)];
#pragma unroll
            for (int i = 0; i < 4; ++i)
#pragma unroll
                for (int j = 0; j < 4; ++j) c[i][j] = fmaf(xr[i], wr[j], c[i][j]);
        }
        __syncthreads();                  // all reads done
        if (cc < 1) WRITE_LDS();
    }

    float* outp = psum + ((size_t)ds * 5120 + R0) * 128;
#pragma unroll
    for (int i = 0; i < 4; ++i)
        *(float4*)&outp[(size_t)(r0 + i) * 128 + h0] = *(const float4*)&c[i][0];

    #undef LOADX
    #undef LOADW
    #undef WRITE_LDS
}

// ---------------------------------------------------------------------------
// proj_reduce: sum 4 d-slices, scale by 2*log2e, write qh_s / kh4 layouts.
// Masked k rows skip.  Grid 640.
// ---------------------------------------------------------------------------
__global__ __launch_bounds__(256) void proj_reduce(
    const float* __restrict__ psum, const int* __restrict__ valid_lens,
    float* __restrict__ qh_s, float4* __restrict__ kh4)
{
    int gid = blockIdx.x * 256 + threadIdx.x;    // [0, 163840)
    int row = gid >> 5, c4 = gid & 31;
    int b = 0, kk = 0;
    if (row >= 1024) {
        int r = row - 1024;
        b = r >> 10; kk = r & 1023;
        if (kk >= valid_lens[b]) return;
    }
    float4 s = make_float4(0.f, 0.f, 0.f, 0.f);
#pragma unroll
    for (int ds = 0; ds < 4; ++ds) {
        float4 v = *(const float4*)&psum[((size_t)ds * 5120 + row) * 128 + c4 * 4];
        s.x += v.x; s.y += v.y; s.z += v.z; s.w += v.w;
    }
    const float SC = 2.0f * LOG2E;
    s.x *= SC; s.y *= SC; s.z *= SC; s.w *= SC;
    if (row < 1024) *(float4*)&qh_s[(size_t)row * 128 + c4 * 4] = s;
    else            kh4[((size_t)(b * 32 + c4)) * K_ + kk] = s;
}

// ---------------------------------------------------------------------------
// attn_part: 2048 blocks x 256 thr (4 waves), item = (b, 8-q tile, 64-k
// chunk); ~1024 active.  LDS ~14.6 KB -> 7+ blocks/CU (was 5; otmp removed).
// Phase B: 4-way h-split (hh = wave, 8 hq each), kh prefetch depth 1,
// exp2-tanh (3 VALU + 2 trans / element), 256 elements/thread.
// Combine: all 4 waves, 2 q-rows each.
// Phase D: per-thread float2 column (256 cols) x 8 q-rows x full klen —
// same FMA/bytes as the old k-split, but no otmp / no extra sync.
// ---------------------------------------------------------------------------
__global__ __launch_bounds__(256) void attn_part(
    const float* __restrict__ qh_s, const float4* __restrict__ kh4,
    const float* __restrict__ wvg,  const int* __restrict__ valid_lens,
    const float* __restrict__ vin,
    float* __restrict__ s_part, float* __restrict__ o_part)
{
    __shared__ float  qv[1024];
    __shared__ float  wvs[128];
    __shared__ float  ptmp[4][8][64];
    __shared__ float  p[8][64];
    __shared__ float  sred[8];

    const int t   = threadIdx.x;
    const int bid = blockIdx.x;
    const int qt  = bid & 31, kc = (bid >> 5) & 15, b = bid >> 9;
    const int q0  = qt * 8;
    const int vl  = valid_lens[b];
    const int kbase = kc * 64;
    if (kbase >= vl) return;
    const int klen = min(64, vl - kbase);

#pragma unroll
    for (int i = 0; i < 4; ++i)
        qv[t + i * 256] = qh_s[(size_t)(b*Q_ + q0) * H_ + t + i * 256];
    if (t < 128) wvs[t] = wvg[t] * (-2.0f * LOG2E);
    __syncthreads();

    const int k  = t & 63;              // k within chunk
    const int hh = t >> 6;              // h-quarter (== wave id)
    const bool active = k < klen;

    // ---- Phase B: scores (4-way h-split, kh prefetch depth 1) ----
    float acc[8] = {};
    if (active) {
        const float4* khp = kh4 + (size_t)b * 32 * K_ + (kbase + k)
                          + (size_t)(hh * 8) * K_;
        const int hq0 = hh * 8;
        float4 kxn = khp[0];
#pragma unroll
        for (int i = 0; i < 8; ++i) {
            float4 kx = kxn;
            int ni = (i < 7) ? i + 1 : 7;
            kxn = khp[(size_t)ni * K_];
            const int hq = hq0 + i;
            float w4[4], kxa[4];
            *(float4*)&w4[0]  = *(const float4*)&wvs[hq*4];
            *(float4*)&kxa[0] = kx;
#pragma unroll
            for (int qi = 0; qi < 8; ++qi) {
                float q4[4];
                *(float4*)&q4[0] = *(const float4*)&qv[qi*128 + hq*4];
#pragma unroll
                for (int j = 0; j < 4; ++j) {
                    float tt = __builtin_amdgcn_exp2f(q4[j] + kxa[j]);
                    float rr = __builtin_amdgcn_rcpf(tt + 1.0f);
                    acc[qi] = fmaf(w4[j], rr, acc[qi]);
                }
            }
        }
    }
#pragma unroll
    for (int qi = 0; qi < 8; ++qi) ptmp[hh][qi][k] = acc[qi];
    __syncthreads();

    // ---- combine: each wave finishes 2 q-rows ----
    {
        const int qia = hh * 2;
#pragma unroll
        for (int q2 = 0; q2 < 2; ++q2) {
            const int qi = qia + q2;
            float a = ptmp[0][qi][k] + ptmp[1][qi][k]
                    + ptmp[2][qi][k] + ptmp[3][qi][k];
            // a is already log2(p) (all scale factors folded upstream)
            float e = active ? __builtin_amdgcn_exp2f(a) : 0.f;
            p[qi][k] = e;
            float s = e;
#pragma unroll
            for (int off = 32; off > 0; off >>= 1) s += __shfl_xor(s, off);
            if (k == 0) sred[qi] = s;
        }
    }
    __syncthreads();                    // p + sred ready

    if (t < 8)
        s_part[(size_t)(b*Q_ + q0 + t) * 16 + kc] = sred[t];

    // ---- Phase D: partial PV (float2 col per thread, full klen) ----
    const int col2 = t;                 // float2 column 0..255
    const float2* vb2 = (const float2*)vin + ((size_t)b * K_ + kbase) * 256;

    float2 o[8];
#pragma unroll
    for (int qi = 0; qi < 8; ++qi) o[qi] = make_float2(0.f, 0.f);

    int kk = 0;
    const int nfull = klen >> 2;
    if (nfull > 0) {
        float2 n0v = vb2[(size_t)0 * 256 + col2];
        float2 n1v = vb2[(size_t)1 * 256 + col2];
        float2 n2v = vb2[(size_t)2 * 256 + col2];
        float2 n3v = vb2[(size_t)3 * 256 + col2];
        for (int g = 0; g < nfull; ++g) {
            float2 v0 = n0v, v1 = n1v, v2 = n2v, v3 = n3v;
            int kn = kk + 4;
            if (g + 1 < nfull) {
                n0v = vb2[(size_t)(kn+0)*256 + col2];
                n1v = vb2[(size_t)(kn+1)*256 + col2];
                n2v = vb2[(size_t)(kn+2)*256 + col2];
                n3v = vb2[(size_t)(kn+3)*256 + col2];
            }
#pragma unroll
            for (int qi = 0; qi < 8; ++qi) {
                float4 pq = *(const float4*)&p[qi][kk];   // uniform -> broadcast
                o[qi].x += pq.x*v0.x + pq.y*v1.x + pq.z*v2.x + pq.w*v3.x;
                o[qi].y += pq.x*v0.y + pq.y*v1.y + pq.z*v2.y + pq.w*v3.y;
            }
            kk = kn;
        }
    }
    for (; kk < klen; ++kk) {
        float2 v0 = vb2[(size_t)kk*256 + col2];
#pragma unroll
        for (int qi = 0; qi < 8; ++qi) {
            float pk = p[qi][kk];
            o[qi].x += pk*v0.x; o[qi].y += pk*v0.y;
        }
    }

#pragma unroll
    for (int qi = 0; qi < 8; ++qi) {
        size_t row = (size_t)b*Q_ + q0 + qi;
        *(float2*)&o_part[((size_t)kc * 1024 + row) * 512 + col2 * 2] = o[qi];
    }
}

// ---------------------------------------------------------------------------
// finalize: out[row][col] = (Sum_{ch<nch} o_part[ch][row][col]) * rcp(Sum s).
// nch = ceil(vl/64) <= 16.  (o_part rows are 512 contiguous floats; float4
// view is layout-compatible with attn's float2 writes.)
// ---------------------------------------------------------------------------
__global__ __launch_bounds__(256) void finalize_kernel(
    const float4* __restrict__ o_part, const float* __restrict__ s_part,
    const int* __restrict__ valid_lens, float4* __restrict__ out)
{
    int gid = blockIdx.x * 256 + threadIdx.x;     // [0, 131072)
    int row = gid >> 7, col = gid & 127;
    int b = row >> 8;
    int nch = (valid_lens[b] + 63) >> 6;
    float ssum = 0.f;
    float4 o = make_float4(0.f, 0.f, 0.f, 0.f);
    for (int ch = 0; ch < nch; ++ch) {
        ssum += s_part[(size_t)row * 16 + ch];
        float4 r = o_part[((size_t)ch * 1024 + row) * 128 + col];
        o.x += r.x; o.y += r.y; o.z += r.z; o.w += r.w;
    }
    float rs = __builtin_amdgcn_rcpf(ssum);
    out[gid] = make_float4(o.x*rs, o.y*rs, o.z*rs, o.w*rs);
}

extern "C" void kernel_launch(void* const* d_in, const int* in_sizes, int n_in,
                              void* d_out, int out_size, void* d_ws, size_t ws_size,
                              hipStream_t stream)
{
    const float* q  = (const float*)d_in[0];
    const float* k  = (const float*)d_in[1];
    const float* v  = (const float*)d_in[2];
    const int*   vl = (const int*)d_in[3];
    const float* wq = (const float*)d_in[4];
    const float* wk = (const float*)d_in[5];
    const float* wv = (const float*)d_in[6];
    float* out = (float*)d_out;

    float* qh_s  = (float*)d_ws;                      //  131072 f
    float* kh4   = qh_s  + (size_t)B_*Q_*H_;          //  524288 f
    float* s_prt = kh4   + (size_t)B_*H_*K_;          //   16384 f
    float* o_prt = s_prt + (size_t)B_*Q_*16;          // 8388608 f (32 MB)
    float* psum  = o_prt + (size_t)16*B_*Q_*DV_;      // 2621440 f (10.5 MB)

    proj_part      <<<dim3(640),  dim3(256), 0, stream>>>(q, k, wq, wk, vl, psum);
    proj_reduce    <<<dim3(640),  dim3(256), 0, stream>>>(psum, vl, qh_s, (float4*)kh4);
    attn_part      <<<dim3(2048), dim3(256), 0, stream>>>(qh_s, (const float4*)kh4, wv, vl, v, s_prt, o_prt);
    finalize_kernel<<<dim3(512),  dim3(256), 0, stream>>>((const float4*)o_prt, s_prt, vl, (float4*)out);
}

// Round 7
// 111.294 us; speedup vs baseline: 1.5698x; 1.0341x over previous
//
#include <hip/hip_runtime.h>

// AdditiveAttention: B=4, Q=256, K=1024, DQ=DK=DV=512, H=128
#define B_ 4
#define Q_ 256
#define K_ 1024
#define D_ 512
#define H_ 128
#define DV_ 512
#define LOG2E 1.4426950408889634f

// tanh via exp2: tanh(x) = 1 - 2/(1+e^{2x}).  SUM_h w_h cancels in softmax:
// p = exp2( SUM_h (-2*log2e*w_h) * rcp(1 + exp2(2*log2e*(qh+kh))) ).
//
// Round-7: factor the inner exp2.  exp2(SC*(qh+kh)) = eq * ek with
// eq = exp2(SC*qh) (131k values), ek = exp2(SC*kh) (524k values), both
// materialized once in proj_reduce.  attn phase B per element becomes
// {mul, add, rcp, fma} = 3 VALU + 1 trans — trans ops HALVE (the r6
// counters showed attn is pipe-floor bound: trans 6.8us was the largest
// term).  Structure is byte-identical to the 115.09us r6 kernel.

// ---------------------------------------------------------------------------
// proj_part: tile = 32 rows x 128 h x 128 d (2 LDS chunks of 64 d).
// Grid 640 = [ds:4 == bid&3][tile:160 = 32 q + 128 k].  4 waves = h-quadrants,
// lane micro 4r x 4h.  40 KB LDS, XOR-swizzled transposed staging
// (write-conflict-free), next-chunk global loads overlap compute (T14).
// Epilogue: float4 partials -> psum[ds] (no atomics, no cross-block reduce).
// ---------------------------------------------------------------------------
__global__ __launch_bounds__(256) void proj_part(
    const float* __restrict__ qin, const float* __restrict__ kin,
    const float* __restrict__ wq,  const float* __restrict__ wk,
    const int* __restrict__ valid_lens, float* __restrict__ psum)
{
    __shared__ float Xs[64 * 32];    //  8 KB, [d][row],  col ^= ((d>>2)&7)<<2
    __shared__ float Ws[64 * 128];   // 32 KB, [d][h],    col ^= ((d>>2)&7)<<2

    const int t = threadIdx.x, bid = blockIdx.x;
    const int ds = bid & 3, tile = bid >> 2;     // tile 0..159
    const float* X; const float* W;
    int R0;
    if (tile < 32) { X = qin + (size_t)tile * 32 * D_; W = wq; R0 = tile * 32; }
    else {
        int kt = tile - 32, kb = kt >> 5, kr0 = (kt & 31) * 32;
        if (kr0 >= valid_lens[kb]) return;
        X = kin + ((size_t)kb * K_ + kr0) * D_;
        W = wk;
        R0 = 1024 + kt * 32;
    }

    const int xrow  = (t + 0) >> 4, xdq = (t & 15) * 4;
    const int xrow1 = (t + 256) >> 4;
    float4 xr0, xr1, wr8[8];

    #define LOADX(c) do { \
        xr0 = *(const float4*)&X[(size_t)xrow  * D_ + (c)*64 + xdq]; \
        xr1 = *(const float4*)&X[(size_t)xrow1 * D_ + (c)*64 + xdq]; } while (0)
    #define LOADW(c) do { \
        _Pragma("unroll") \
        for (int i = 0; i < 8; ++i) { \
            int idx = t + i * 256; \
            wr8[i] = *(const float4*)&W[(size_t)(idx >> 4) * D_ + (c)*64 + (idx & 15) * 4]; } } while (0)
    #define WRITE_LDS() do { \
        { float v[4]; *(float4*)v = xr0; \
          _Pragma("unroll") \
          for (int j = 0; j < 4; ++j) { int d = xdq + j; \
              Xs[d * 32 + (xrow ^ (((d >> 2) & 7) << 2))] = v[j]; } } \
        { float v[4]; *(float4*)v = xr1; \
          _Pragma("unroll") \
          for (int j = 0; j < 4; ++j) { int d = xdq + j; \
              Xs[d * 32 + (xrow1 ^ (((d >> 2) & 7) << 2))] = v[j]; } } \
        _Pragma("unroll") \
        for (int i = 0; i < 8; ++i) { \
            int idx = t + i * 256; int h = idx >> 4, dq = (idx & 15) * 4; \
            float v[4]; *(float4*)v = wr8[i]; \
            _Pragma("unroll") \
            for (int j = 0; j < 4; ++j) { int d = dq + j; \
                Ws[d * 128 + (h ^ (((d >> 2) & 7) << 2))] = v[j]; } } } while (0)

    const int wid = t >> 6, lane = t & 63;
    const int r0 = (lane & 7) * 4;                    // 4 rows
    const int h0 = wid * 32 + (lane >> 3) * 4;        // 4 h
    float c[4][4] = {};

    const int c0 = ds * 2;                            // 2 chunks: c0, c0+1
    LOADX(c0); LOADW(c0);
    WRITE_LDS();

    for (int cc = 0; cc < 2; ++cc) {
        __syncthreads();                  // LDS chunk ready
        if (cc < 1) { LOADX(c0 + 1); LOADW(c0 + 1); }
#pragma unroll 8
        for (int kk = 0; kk < 64; ++kk) {
            const int xc = ((kk >> 2) & 7) << 2;
            float xr[4], wr[4];
            *(float4*)&xr[0] = *(const float4*)&Xs[kk * 32  + (r0 ^ xc)];
            *(float4*)&wr[0] = *(const float4*)&Ws[kk * 128 + (h0 ^ xc)];
#pragma unroll
            for (int i = 0; i < 4; ++i)
#pragma unroll
                for (int j = 0; j < 4; ++j) c[i][j] = fmaf(xr[i], wr[j], c[i][j]);
        }
        __syncthreads();                  // all reads done
        if (cc < 1) WRITE_LDS();
    }

    float* outp = psum + ((size_t)ds * 5120 + R0) * 128;
#pragma unroll
    for (int i = 0; i < 4; ++i)
        *(float4*)&outp[(size_t)(r0 + i) * 128 + h0] = *(const float4*)&c[i][0];

    #undef LOADX
    #undef LOADW
    #undef WRITE_LDS
}

// ---------------------------------------------------------------------------
// proj_reduce: sum 4 d-slices, then store eq = exp2(2*log2e * qh) and
// ek = exp2(2*log2e * kh)  (the factored inner exponentials; 1 extra trans
// per output value).  Masked k rows skip.  Grid 640.
// ---------------------------------------------------------------------------
__global__ __launch_bounds__(256) void proj_reduce(
    const float* __restrict__ psum, const int* __restrict__ valid_lens,
    float* __restrict__ qh_s, float4* __restrict__ kh4)
{
    int gid = blockIdx.x * 256 + threadIdx.x;    // [0, 163840)
    int row = gid >> 5, c4 = gid & 31;
    int b = 0, kk = 0;
    if (row >= 1024) {
        int r = row - 1024;
        b = r >> 10; kk = r & 1023;
        if (kk >= valid_lens[b]) return;
    }
    float4 s = make_float4(0.f, 0.f, 0.f, 0.f);
#pragma unroll
    for (int ds = 0; ds < 4; ++ds) {
        float4 v = *(const float4*)&psum[((size_t)ds * 5120 + row) * 128 + c4 * 4];
        s.x += v.x; s.y += v.y; s.z += v.z; s.w += v.w;
    }
    const float SC = 2.0f * LOG2E;
    s.x = __builtin_amdgcn_exp2f(s.x * SC);
    s.y = __builtin_amdgcn_exp2f(s.y * SC);
    s.z = __builtin_amdgcn_exp2f(s.z * SC);
    s.w = __builtin_amdgcn_exp2f(s.w * SC);
    if (row < 1024) *(float4*)&qh_s[(size_t)row * 128 + c4 * 4] = s;
    else            kh4[((size_t)(b * 32 + c4)) * K_ + kk] = s;
}

// ---------------------------------------------------------------------------
// attn_part: 2048 blocks x 256 thr (4 waves), item = (b, 8-q tile, 64-k
// chunk); ~1024 active.  LDS ~14.6 KB.
// Phase B: 4-way h-split (hh = wave, 8 hq each), ek prefetch depth 1,
// factored sigmoid: acc += w' * rcp(eq*ek + 1)  — 3 VALU + 1 trans / elem.
// Combine: all 4 waves, 2 q-rows each.
// Phase D: per-thread float2 column (256 cols) x 8 q-rows x full klen.
// ---------------------------------------------------------------------------
__global__ __launch_bounds__(256) void attn_part(
    const float* __restrict__ qh_s, const float4* __restrict__ kh4,
    const float* __restrict__ wvg,  const int* __restrict__ valid_lens,
    const float* __restrict__ vin,
    float* __restrict__ s_part, float* __restrict__ o_part)
{
    __shared__ float  qv[1024];
    __shared__ float  wvs[128];
    __shared__ float  ptmp[4][8][64];
    __shared__ float  p[8][64];
    __shared__ float  sred[8];

    const int t   = threadIdx.x;
    const int bid = blockIdx.x;
    const int qt  = bid & 31, kc = (bid >> 5) & 15, b = bid >> 9;
    const int q0  = qt * 8;
    const int vl  = valid_lens[b];
    const int kbase = kc * 64;
    if (kbase >= vl) return;
    const int klen = min(64, vl - kbase);

#pragma unroll
    for (int i = 0; i < 4; ++i)
        qv[t + i * 256] = qh_s[(size_t)(b*Q_ + q0) * H_ + t + i * 256];
    if (t < 128) wvs[t] = wvg[t] * (-2.0f * LOG2E);
    __syncthreads();

    const int k  = t & 63;              // k within chunk
    const int hh = t >> 6;              // h-quarter (== wave id)
    const bool active = k < klen;

    // ---- Phase B: scores (4-way h-split, ek prefetch depth 1) ----
    float acc[8] = {};
    if (active) {
        const float4* khp = kh4 + (size_t)b * 32 * K_ + (kbase + k)
                          + (size_t)(hh * 8) * K_;
        const int hq0 = hh * 8;
        float4 kxn = khp[0];
#pragma unroll
        for (int i = 0; i < 8; ++i) {
            float4 kx = kxn;
            int ni = (i < 7) ? i + 1 : 7;
            kxn = khp[(size_t)ni * K_];
            const int hq = hq0 + i;
            float w4[4], kxa[4];
            *(float4*)&w4[0]  = *(const float4*)&wvs[hq*4];
            *(float4*)&kxa[0] = kx;
#pragma unroll
            for (int qi = 0; qi < 8; ++qi) {
                float q4[4];
                *(float4*)&q4[0] = *(const float4*)&qv[qi*128 + hq*4];
#pragma unroll
                for (int j = 0; j < 4; ++j) {
                    float tt = q4[j] * kxa[j];          // eq * ek
                    float rr = __builtin_amdgcn_rcpf(tt + 1.0f);
                    acc[qi] = fmaf(w4[j], rr, acc[qi]);
                }
            }
        }
    }
#pragma unroll
    for (int qi = 0; qi < 8; ++qi) ptmp[hh][qi][k] = acc[qi];
    __syncthreads();

    // ---- combine: each wave finishes 2 q-rows ----
    {
        const int qia = hh * 2;
#pragma unroll
        for (int q2 = 0; q2 < 2; ++q2) {
            const int qi = qia + q2;
            float a = ptmp[0][qi][k] + ptmp[1][qi][k]
                    + ptmp[2][qi][k] + ptmp[3][qi][k];
            // a is already log2(p) (all scale factors folded upstream)
            float e = active ? __builtin_amdgcn_exp2f(a) : 0.f;
            p[qi][k] = e;
            float s = e;
#pragma unroll
            for (int off = 32; off > 0; off >>= 1) s += __shfl_xor(s, off);
            if (k == 0) sred[qi] = s;
        }
    }
    __syncthreads();                    // p + sred ready

    if (t < 8)
        s_part[(size_t)(b*Q_ + q0 + t) * 16 + kc] = sred[t];

    // ---- Phase D: partial PV (float2 col per thread, full klen) ----
    const int col2 = t;                 // float2 column 0..255
    const float2* vb2 = (const float2*)vin + ((size_t)b * K_ + kbase) * 256;

    float2 o[8];
#pragma unroll
    for (int qi = 0; qi < 8; ++qi) o[qi] = make_float2(0.f, 0.f);

    int kk = 0;
    const int nfull = klen >> 2;
    if (nfull > 0) {
        float2 n0v = vb2[(size_t)0 * 256 + col2];
        float2 n1v = vb2[(size_t)1 * 256 + col2];
        float2 n2v = vb2[(size_t)2 * 256 + col2];
        float2 n3v = vb2[(size_t)3 * 256 + col2];
        for (int g = 0; g < nfull; ++g) {
            float2 v0 = n0v, v1 = n1v, v2 = n2v, v3 = n3v;
            int kn = kk + 4;
            if (g + 1 < nfull) {
                n0v = vb2[(size_t)(kn+0)*256 + col2];
                n1v = vb2[(size_t)(kn+1)*256 + col2];
                n2v = vb2[(size_t)(kn+2)*256 + col2];
                n3v = vb2[(size_t)(kn+3)*256 + col2];
            }
#pragma unroll
            for (int qi = 0; qi < 8; ++qi) {
                float4 pq = *(const float4*)&p[qi][kk];   // uniform -> broadcast
                o[qi].x += pq.x*v0.x + pq.y*v1.x + pq.z*v2.x + pq.w*v3.x;
                o[qi].y += pq.x*v0.y + pq.y*v1.y + pq.z*v2.y + pq.w*v3.y;
            }
            kk = kn;
        }
    }
    for (; kk < klen; ++kk) {
        float2 v0 = vb2[(size_t)kk*256 + col2];
#pragma unroll
        for (int qi = 0; qi < 8; ++qi) {
            float pk = p[qi][kk];
            o[qi].x += pk*v0.x; o[qi].y += pk*v0.y;
        }
    }

#pragma unroll
    for (int qi = 0; qi < 8; ++qi) {
        size_t row = (size_t)b*Q_ + q0 + qi;
        *(float2*)&o_part[((size_t)kc * 1024 + row) * 512 + col2 * 2] = o[qi];
    }
}

// ---------------------------------------------------------------------------
// finalize: out[row][col] = (Sum_{ch<nch} o_part[ch][row][col]) * rcp(Sum s).
// nch = ceil(vl/64) <= 16.
// ---------------------------------------------------------------------------
__global__ __launch_bounds__(256) void finalize_kernel(
    const float4* __restrict__ o_part, const float* __restrict__ s_part,
    const int* __restrict__ valid_lens, float4* __restrict__ out)
{
    int gid = blockIdx.x * 256 + threadIdx.x;     // [0, 131072)
    int row = gid >> 7, col = gid & 127;
    int b = row >> 8;
    int nch = (valid_lens[b] + 63) >> 6;
    float ssum = 0.f;
    float4 o = make_float4(0.f, 0.f, 0.f, 0.f);
    for (int ch = 0; ch < nch; ++ch) {
        ssum += s_part[(size_t)row * 16 + ch];
        float4 r = o_part[((size_t)ch * 1024 + row) * 128 + col];
        o.x += r.x; o.y += r.y; o.z += r.z; o.w += r.w;
    }
    float rs = __builtin_amdgcn_rcpf(ssum);
    out[gid] = make_float4(o.x*rs, o.y*rs, o.z*rs, o.w*rs);
}

extern "C" void kernel_launch(void* const* d_in, const int* in_sizes, int n_in,
                              void* d_out, int out_size, void* d_ws, size_t ws_size,
                              hipStream_t stream)
{
    const float* q  = (const float*)d_in[0];
    const float* k  = (const float*)d_in[1];
    const float* v  = (const float*)d_in[2];
    const int*   vl = (const int*)d_in[3];
    const float* wq = (const float*)d_in[4];
    const float* wk = (const float*)d_in[5];
    const float* wv = (const float*)d_in[6];
    float* out = (float*)d_out;

    float* qh_s  = (float*)d_ws;                      //  131072 f
    float* kh4   = qh_s  + (size_t)B_*Q_*H_;          //  524288 f
    float* s_prt = kh4   + (size_t)B_*H_*K_;          //   16384 f
    float* o_prt = s_prt + (size_t)B_*Q_*16;          // 8388608 f (32 MB)
    float* psum  = o_prt + (size_t)16*B_*Q_*DV_;      // 2621440 f (10.5 MB)

    proj_part      <<<dim3(640),  dim3(256), 0, stream>>>(q, k, wq, wk, vl, psum);
    proj_reduce    <<<dim3(640),  dim3(256), 0, stream>>>(psum, vl, qh_s, (float4*)kh4);
    attn_part      <<<dim3(2048), dim3(256), 0, stream>>>(qh_s, (const float4*)kh4, wv, vl, v, s_prt, o_prt);
    finalize_kernel<<<dim3(512),  dim3(256), 0, stream>>>((const float4*)o_prt, s_prt, vl, (float4*)out);
}